// Round 5
// baseline (256.437 us; speedup 1.0000x reference)
//
#include <hip/hip_runtime.h>
#include <hip/hip_bf16.h>

// SCM_39676907888322: sigmoid-gated cross attention. fp32 I/O, bf16 MFMA compute.
// R5: attn on 32x32x16 MFMA (16 FLOP per LDS byte vs 8), 2-wave blocks of 64
//     Q-rows (grid 576 balanced), conflict-free P-strip writes, f32x4 epilogue.
//     qkv staging fully coalesced (lanes along n: 128B row segments).

typedef __bf16 bf16;
typedef __bf16 bf16x8 __attribute__((ext_vector_type(8)));
typedef __bf16 bf16x4 __attribute__((ext_vector_type(4)));
typedef float f32x4 __attribute__((ext_vector_type(4)));
typedef float f32x16 __attribute__((ext_vector_type(16)));

#define NB 8
#define NC 256
#define NCI 128
#define NHW 2304
#define NT32 72    // 2304 / 32  (qkv n-tiles)
#define KPAD 136   // K-tile LDS row stride (64 rows x 128 c)
#define VPAD 72    // V-tile LDS row stride (128 rows x 64 m)
#define PPAD 72    // P strip row stride (32 rows x 64 m)

__global__ __launch_bounds__(256) void wconv_kernel(
    const float* __restrict__ w0, const float* __restrict__ w1,
    const float* __restrict__ w2, const float* __restrict__ w3,
    const float* __restrict__ w4, const float* __restrict__ w5,
    bf16* __restrict__ dst)
{
    int idx = (blockIdx.x * 256 + threadIdx.x) * 8;   // 6*32768 total
    int m = idx >> 15;                                 // matrix id (block-uniform)
    int off = idx & 32767;
    const float* w = (m == 0) ? w0 : (m == 1) ? w1 : (m == 2) ? w2
                   : (m == 3) ? w3 : (m == 4) ? w4 : w5;
    f32x4 a0 = *(const f32x4*)(w + off);
    f32x4 a1 = *(const f32x4*)(w + off + 4);
    bf16x8 o;
    #pragma unroll
    for (int j = 0; j < 4; ++j) { o[j] = (bf16)a0[j]; o[4 + j] = (bf16)a1[j]; }
    *(bf16x8*)(dst + idx) = o;
}

__global__ __launch_bounds__(256) void qkv_kernel(
    const float* __restrict__ x1, const float* __restrict__ x2,
    const bf16* __restrict__ wb,
    const float* __restrict__ bv1, const float* __restrict__ bk1, const float* __restrict__ bq1,
    const float* __restrict__ bv2, const float* __restrict__ bk2, const float* __restrict__ bq2,
    bf16* __restrict__ Qt, bf16* __restrict__ Kt, bf16* __restrict__ Vt,
    float* __restrict__ out)
{
    // Xt[n][c] bf16, 32 rows, padded stride 264
    __shared__ __align__(16) bf16 Xt[32 * 264];

    int gid = blockIdx.x;
    int nt = gid % NT32;
    int s = (gid / NT32) & 1;
    int b = gid / (2 * NT32);
    int n0 = nt * 32;

    const float* x = s ? x2 : x1;
    // wb layout: [v1,k1,q1,v2,k2,q2] each 128*256
    const bf16* wv = wb + (size_t)(s * 3 + 0) * (NCI * NC);
    const bf16* wk = wb + (size_t)(s * 3 + 1) * (NCI * NC);
    const bf16* wq = wb + (size_t)(s * 3 + 2) * (NCI * NC);
    const float* bv = s ? bv2 : bv1;
    const float* bk = s ? bk2 : bk1;
    const float* bq = s ? bq2 : bq1;
    float* outy = out + (size_t)s * (NB * 384 * NHW);

    int tid = threadIdx.x;
    // Coalesced staging: lane covers 16B along n; 8 lanes = one row's 128B.
    // Per pass: wave touches 8 rows x 128B (full lines). 8 passes cover 256 c.
    {
        int noff = (tid & 7) * 4;        // 0,4,...,28
        int cbase = tid >> 3;            // 0..31
        #pragma unroll
        for (int i = 0; i < 8; ++i) {
            int c = cbase + i * 32;
            const float* src = x + ((size_t)(b * NC + c) * NHW + n0 + noff);
            f32x4 a = *(const f32x4*)src;
            *(f32x4*)(outy + ((size_t)(b * 384 + c) * NHW + n0 + noff)) = a;
            #pragma unroll
            for (int j = 0; j < 4; ++j)
                Xt[(noff + j) * 264 + c] = (bf16)a[j];
        }
    }
    __syncthreads();

    int lane = tid & 63;
    int wid = tid >> 6;                  // wave 0..3 -> ci strip of 32
    int row = lane & 15, quad = lane >> 4;
    int ci_base = wid * 32;

    f32x4 acc[3][2][2];                  // [q,k,v][mi][j]
    #pragma unroll
    for (int t = 0; t < 3; ++t)
        #pragma unroll
        for (int mi = 0; mi < 2; ++mi)
            #pragma unroll
            for (int j = 0; j < 2; ++j)
                acc[t][mi][j] = (f32x4){0.f, 0.f, 0.f, 0.f};

    const bf16* wptr[3] = {wq, wk, wv};
    #pragma unroll
    for (int ks = 0; ks < 8; ++ks) {
        int c0 = ks * 32 + quad * 8;
        bf16x8 bfrag[2];
        #pragma unroll
        for (int j = 0; j < 2; ++j)
            bfrag[j] = *(const bf16x8*)&Xt[(j * 16 + row) * 264 + c0];
        #pragma unroll
        for (int t = 0; t < 3; ++t) {
            #pragma unroll
            for (int mi = 0; mi < 2; ++mi) {
                bf16x8 afrag = *(const bf16x8*)&wptr[t][(size_t)(ci_base + mi * 16 + row) * NC + c0];
                #pragma unroll
                for (int j = 0; j < 2; ++j)
                    acc[t][mi][j] = __builtin_amdgcn_mfma_f32_16x16x32_bf16(
                        afrag, bfrag[j], acc[t][mi][j], 0, 0, 0);
            }
        }
    }

    // Epilogue: +bias (fp32), write Qt/Kt (n,128) bf16 8B stores, V (128,n) bf16 scalar.
    size_t qkbase = ((size_t)s * NB + b) * NHW * NCI;
    size_t vbase  = ((size_t)s * NB + b) * NCI * NHW;
    #pragma unroll
    for (int mi = 0; mi < 2; ++mi) {
        int ci0 = ci_base + mi * 16 + quad * 4;
        f32x4 bq4 = *(const f32x4*)&bq[ci0];
        f32x4 bk4 = *(const f32x4*)&bk[ci0];
        f32x4 bv4 = *(const f32x4*)&bv[ci0];
        #pragma unroll
        for (int j = 0; j < 2; ++j) {
            int n = n0 + j * 16 + row;   // D col = lane&15
            bf16x4 pk;
            #pragma unroll
            for (int r = 0; r < 4; ++r) pk[r] = (bf16)(acc[0][mi][j][r] + bq4[r]);
            *(bf16x4*)&Qt[qkbase + (size_t)n * NCI + ci0] = pk;
            #pragma unroll
            for (int r = 0; r < 4; ++r) pk[r] = (bf16)(acc[1][mi][j][r] + bk4[r]);
            *(bf16x4*)&Kt[qkbase + (size_t)n * NCI + ci0] = pk;
            #pragma unroll
            for (int r = 0; r < 4; ++r)
                Vt[vbase + (size_t)(ci0 + r) * NHW + n] = (bf16)(acc[2][mi][j][r] + bv4[r]);
        }
    }
}

__global__ __launch_bounds__(128) void attn_kernel(
    const bf16* __restrict__ Qt, const bf16* __restrict__ Kt, const bf16* __restrict__ Vt,
    float* __restrict__ out)
{
    __shared__ __align__(16) bf16 KT[64 * KPAD];    // 17408 B: K-tile [n 64][c 128]
    __shared__ __align__(16) bf16 VT[128 * VPAD];   // 18432 B: V-tile [c 128][m 64]
    __shared__ __align__(16) bf16 P[2][32 * PPAD];  //  9216 B: per-wave P strips

    int gid = blockIdx.x;
    // XCD swizzle: gid&7 selects XCD; one batch b (both dirs) per XCD -> ~3.5MB in L2.
    int pair = (gid & 7) * 2 + ((gid >> 3) & 1);    // 0..15
    int nt = gid >> 4;                               // 0..35
    int dir = pair & 1;
    int b = pair >> 1;
    int n0 = nt * 64;

    int tid = threadIdx.x;               // 0..127 (2 waves)
    int lane = tid & 63, w = tid >> 6;
    int l32 = lane & 31, h = lane >> 5;

    int sq = dir, skv = dir ^ 1;
    const bf16* q = Qt + ((size_t)sq  * NB + b) * (NHW * NCI);
    const bf16* k = Kt + ((size_t)skv * NB + b) * (NHW * NCI);
    const bf16* v = Vt + ((size_t)skv * NB + b) * (NCI * NHW);
    float* outy = out + (size_t)dir * (NB * 384 * NHW) + ((size_t)b * 384 + 256) * NHW;

    // Staging assignment (coalesced): K: 8 rows/pass x 16 chunks; V: 16 rows/pass x 8 chunks.
    int krow = tid >> 4, kch = tid & 15;
    int vrow = tid >> 3, vch = tid & 7;

    int nw = n0 + w * 32;                // this wave's 32 Q rows
    // Q A-frags (32x32x16): A[m=l32][k=h*8+j], 8 k-steps of 16, resident.
    bf16x8 qf[8];
    #pragma unroll
    for (int ks = 0; ks < 8; ++ks)
        qf[ks] = *(const bf16x8*)&q[(size_t)(nw + l32) * NCI + ks * 16 + h * 8];

    f32x16 o[4];                         // O acc: 32 rows x 128 c (4 n-tiles of 32)
    #pragma unroll
    for (int ct = 0; ct < 4; ++ct)
        #pragma unroll
        for (int r = 0; r < 16; ++r) o[ct][r] = 0.f;

    bf16* Pw = P[w];

    // Prefetch tile 0 into registers.
    bf16x8 kreg[8], vreg[8];
    #pragma unroll
    for (int i = 0; i < 8; ++i) {
        kreg[i] = *(const bf16x8*)&k[(size_t)(krow + 8 * i) * NCI + kch * 8];
        vreg[i] = *(const bf16x8*)&v[(size_t)(vrow + 16 * i) * NHW + vch * 8];
    }

    for (int mt = 0; mt < 36; ++mt) {
        __syncthreads();                 // prior tile's LDS reads complete
        #pragma unroll
        for (int i = 0; i < 8; ++i) {
            *(bf16x8*)&KT[(krow + 8 * i) * KPAD + kch * 8] = kreg[i];
            *(bf16x8*)&VT[(vrow + 16 * i) * VPAD + vch * 8] = vreg[i];
        }
        __syncthreads();                 // tile mt visible
        if (mt < 35) {                   // prefetch mt+1 (waited on at next ds_write)
            size_t ko = (size_t)(mt + 1) * 64 * NCI;
            int vo = (mt + 1) * 64;
            #pragma unroll
            for (int i = 0; i < 8; ++i) {
                kreg[i] = *(const bf16x8*)&k[ko + (size_t)(krow + 8 * i) * NCI + kch * 8];
                vreg[i] = *(const bf16x8*)&v[(size_t)(vrow + 16 * i) * NHW + vo + vch * 8];
            }
        }
        // S = Q K^T : 32 Q-rows x 64 K-rows, two 32x32 accumulators.
        f32x16 sacc[2];
        #pragma unroll
        for (int j32 = 0; j32 < 2; ++j32)
            #pragma unroll
            for (int r = 0; r < 16; ++r) sacc[j32][r] = 0.f;
        #pragma unroll
        for (int ks = 0; ks < 8; ++ks) {
            #pragma unroll
            for (int j32 = 0; j32 < 2; ++j32) {
                bf16x8 kf = *(const bf16x8*)&KT[(j32 * 32 + l32) * KPAD + ks * 16 + h * 8];
                sacc[j32] = __builtin_amdgcn_mfma_f32_32x32x16_bf16(qf[ks], kf, sacc[j32], 0, 0, 0);
            }
        }
        // sigmoid -> P strip (wave-private; conflict-free write pattern).
        // C/D: col=l32 (K-row), row=(reg&3)+8*(reg>>2)+4*h (Q-row).
        #pragma unroll
        for (int j32 = 0; j32 < 2; ++j32) {
            #pragma unroll
            for (int g = 0; g < 4; ++g) {
                #pragma unroll
                for (int r = 0; r < 4; ++r) {
                    float xv = sacc[j32][g * 4 + r];
                    float e = __expf(-xv);
                    float p = __builtin_amdgcn_rcpf(1.0f + e);
                    Pw[(r + 8 * g + 4 * h) * PPAD + j32 * 32 + l32] = (bf16)p;
                }
            }
        }
        // O += P V^T : A = P[m=32 Q-rows][k=64 m], B = V[n=c][k=m] from LDS.
        #pragma unroll
        for (int ks2 = 0; ks2 < 4; ++ks2) {
            bf16x8 af = *(const bf16x8*)&Pw[l32 * PPAD + ks2 * 16 + h * 8];
            #pragma unroll
            for (int ct = 0; ct < 4; ++ct) {
                bf16x8 vf = *(const bf16x8*)&VT[(ct * 32 + l32) * VPAD + ks2 * 16 + h * 8];
                o[ct] = __builtin_amdgcn_mfma_f32_32x32x16_bf16(af, vf, o[ct], 0, 0, 0);
            }
        }
    }

    // Epilogue: rows (reg&3) are consecutive n -> f32x4 stores, 32B/row segments.
    #pragma unroll
    for (int ct = 0; ct < 4; ++ct) {
        int c = ct * 32 + l32;
        #pragma unroll
        for (int g = 0; g < 4; ++g) {
            f32x4 pk;
            #pragma unroll
            for (int r = 0; r < 4; ++r) pk[r] = o[ct][g * 4 + r];
            *(f32x4*)&outy[(size_t)c * NHW + nw + 8 * g + 4 * h] = pk;
        }
    }
}

extern "C" void kernel_launch(void* const* d_in, const int* in_sizes, int n_in,
                              void* d_out, int out_size, void* d_ws, size_t ws_size,
                              hipStream_t stream) {
    const float* x1  = (const float*)d_in[0];
    const float* x2  = (const float*)d_in[1];
    const float* wv1 = (const float*)d_in[2];  const float* bv1 = (const float*)d_in[3];
    const float* wk1 = (const float*)d_in[4];  const float* bk1 = (const float*)d_in[5];
    const float* wq1 = (const float*)d_in[6];  const float* bq1 = (const float*)d_in[7];
    const float* wv2 = (const float*)d_in[8];  const float* bv2 = (const float*)d_in[9];
    const float* wk2 = (const float*)d_in[10]; const float* bk2 = (const float*)d_in[11];
    const float* wq2 = (const float*)d_in[12]; const float* bq2 = (const float*)d_in[13];
    float* out = (float*)d_out;

    // ws layout (bf16): Qt[2][B][2304][128] | Kt | Vt[2][B][128][2304] | wb[6][128*256]
    size_t per = (size_t)2 * NB * NHW * NCI;
    bf16* Qt = (bf16*)d_ws;
    bf16* Kt = Qt + per;
    bf16* Vt = Kt + per;
    bf16* wb = Vt + per;

    wconv_kernel<<<dim3(96), dim3(256), 0, stream>>>(wv1, wk1, wq1, wv2, wk2, wq2, wb);

    qkv_kernel<<<dim3(NB * 2 * NT32), dim3(256), 0, stream>>>(
        x1, x2, wb, bv1, bk1, bq1, bv2, bk2, bq2, Qt, Kt, Vt, out);

    attn_kernel<<<dim3(NB * 2 * 36), dim3(128), 0, stream>>>(Qt, Kt, Vt, out);
}